// Round 9
// baseline (220.778 us; speedup 1.0000x reference)
//
#include <hip/hip_runtime.h>

// Flash attention B=2,H=8,N=4096,d=64 fp32 in/out (QKV packed [3,16,4096,64]).
// Round 9: kernel-count cut. Cross-round timing shows ~25us fixed overhead per
// graph node (r1: 1 kernel, aux~0; r2/r4: 2 kernels, aux~50; r5/r7/r8: 3
// kernels, aux~73), so split-K + combine is net-negative. This round: 2
// kernels only. Occupancy recovered without split-K via 128-thread blocks
// (2 waves x 64 q-rows, BR=128) -> 512 blocks = 4 blocks/CU x 2 waves = same
// 8 waves/CU as r8 with the same per-wave DS efficiency. Prep's V-transpose
// global writes made coalesced (4 threads per 128B line). Numerics unchanged:
// static-M softmax (tile0 max + 4 folded into MFMA C-init), bf16 P/V.

typedef _Float16 f16x8 __attribute__((ext_vector_type(8)));
typedef _Float16 f16x2 __attribute__((ext_vector_type(2)));
typedef short s16x8 __attribute__((ext_vector_type(8)));
typedef short s16x4 __attribute__((ext_vector_type(4)));
typedef float f32x4 __attribute__((ext_vector_type(4)));

#define NHEADS 16
#define SEQ 4096
#define HDIM 64
#define BR 128   // Q rows per block (2 waves x 64)
#define NH 4     // 16-row h-tiles per wave
#define BC 64    // KV cols per iteration
#define KP 72    // LDS pitch (halves): 144B rows, 16B-aligned
#define PP 72
#define MPAD 4.0f  // M = tile0 row max + MPAD (log2 domain)

__device__ __forceinline__ float fast_exp2(float x) {
#if __has_builtin(__builtin_amdgcn_exp2f)
  return __builtin_amdgcn_exp2f(x);
#else
  return exp2f(x);
#endif
}

__device__ __forceinline__ f16x2 pkrtz(float a, float b) {
  return __builtin_bit_cast(f16x2, __builtin_amdgcn_cvt_pkrtz(a, b));
}

// fp32 -> bf16 RNE (prepass / fallback only)
__device__ __forceinline__ unsigned short f2bf(float f) {
  unsigned u = __builtin_bit_cast(unsigned, f);
  u += 0x7fffu + ((u >> 16) & 1u);
  return (unsigned short)(u >> 16);
}

// two fp32 -> two bf16 by truncation (P >= 0; consistent with fp32 psum)
__device__ __forceinline__ unsigned bfpack2(float a, float b) {
  return (__builtin_bit_cast(unsigned, b) & 0xffff0000u) |
         (__builtin_bit_cast(unsigned, a) >> 16);
}

// ---- fused prepass ----
// blocks [0, 2048):  K fp32 -> fp16, layout preserved [16][4096][64]
// blocks [2048, 3072): V fp32 [16][4096][64] -> bf16 transposed [16][64][4096]
__global__ __launch_bounds__(256) void prep(const float* __restrict__ QKV,
                                            _Float16* __restrict__ K16,
                                            short* __restrict__ Vt) {
  const size_t tensElems = (size_t)NHEADS * SEQ * HDIM;
  __shared__ __align__(16) short T[64 * KP];
  if (blockIdx.x < 2048) {
    const float* Kf = QKV + tensElems;
    size_t i = ((size_t)blockIdx.x * 256 + threadIdx.x) * 8;
    float4 a = *(const float4*)(Kf + i);
    float4 b = *(const float4*)(Kf + i + 4);
    union { f16x8 v; f16x2 h2[4]; } u;
    u.h2[0] = pkrtz(a.x, a.y);
    u.h2[1] = pkrtz(a.z, a.w);
    u.h2[2] = pkrtz(b.x, b.y);
    u.h2[3] = pkrtz(b.z, b.w);
    *(f16x8*)(K16 + i) = u.v;
  } else {
    const int vb = blockIdx.x - 2048;
    const int bh = vb >> 6;
    const int nt = vb & 63;
    const float* Vh = QKV + 2 * tensElems + (size_t)bh * SEQ * HDIM +
                      (size_t)nt * 64 * HDIM;
    const int t = threadIdx.x;
    #pragma unroll
    for (int p = 0; p < 4; ++p) {
      int idx = t + p * 256;
      int row = idx >> 4, c4 = (idx & 15) << 2;
      float4 v = *(const float4*)(Vh + row * HDIM + c4);
      s16x4 h;
      h[0] = (short)f2bf(v.x); h[1] = (short)f2bf(v.y);
      h[2] = (short)f2bf(v.z); h[3] = (short)f2bf(v.w);
      *(s16x4*)&T[row * KP + c4] = h;
    }
    __syncthreads();
    // coalesced output: thread -> (d = t>>2, 16-n chunk); 4 threads = 128B line
    const int d = t >> 2, nc = (t & 3) << 4;
    s16x8 o0, o1;
    #pragma unroll
    for (int j = 0; j < 8; ++j) o0[j] = T[(nc + j) * KP + d];
    #pragma unroll
    for (int j = 0; j < 8; ++j) o1[j] = T[(nc + 8 + j) * KP + d];
    short* out = Vt + (size_t)bh * HDIM * SEQ + (size_t)d * SEQ + nt * 64 + nc;
    *(s16x8*)out = o0;
    *(s16x8*)(out + 8) = o1;
  }
}

// ---- main kernel ----
template <bool PRE>
__global__ __launch_bounds__(128, 2) void flash_attn(const float* __restrict__ QKV,
                                                     const _Float16* __restrict__ K16g,
                                                     const short* __restrict__ Vt16,
                                                     float* __restrict__ Out) {
  const size_t headElems = (size_t)SEQ * HDIM;
  const size_t tensElems = (size_t)NHEADS * headElems;
  const int bh = blockIdx.x & 15;   // same-bh blocks 16 apart -> same XCD
  const int qt = blockIdx.x >> 4;   // 0..31

  const float* Q = QKV + (size_t)bh * headElems;
  const float* Kf = QKV + tensElems + (size_t)bh * headElems;
  const float* Vf = QKV + 2 * tensElems + (size_t)bh * headElems;
  const _Float16* Kg16 = K16g + (size_t)bh * headElems;  // [n][d] fp16
  const short* Vg16 = Vt16 + (size_t)bh * headElems;     // [d][n] bf16
  float* O = Out + (size_t)bh * headElems;

  const int tid = threadIdx.x;
  const int wave = tid >> 6;        // 0..1
  const int lane = tid & 63;
  const int g = lane >> 4;
  const int l16 = lane & 15;

  __shared__ __align__(16) _Float16 Ks[BC * KP];    // [kv][d] fp16   9216 B
  __shared__ __align__(16) short Vs[HDIM * KP];     // [d][kv] bf16   9216 B
  __shared__ __align__(16) short Ps[2][NH][16 * PP];// bf16          18432 B

  // ---- Q fragments (B operand of S^T): lane l16 = Q row, k = g*8+j ----
  const float LOG2E = 1.4426950408889634f;
  const int qbase = qt * BR + wave * (16 * NH);
  f16x8 qf[NH][2];
  #pragma unroll
  for (int h = 0; h < NH; ++h) {
    const float* qp = Q + (size_t)(qbase + h * 16 + l16) * HDIM + g * 8;
    #pragma unroll
    for (int c = 0; c < 2; ++c) {
      float4 a = *(const float4*)(qp + c * 32);
      float4 b = *(const float4*)(qp + c * 32 + 4);
      union { f16x8 v; f16x2 h2[4]; } u;
      u.h2[0] = pkrtz(a.x * LOG2E, a.y * LOG2E);
      u.h2[1] = pkrtz(a.z * LOG2E, a.w * LOG2E);
      u.h2[2] = pkrtz(b.x * LOG2E, b.y * LOG2E);
      u.h2[3] = pkrtz(b.z * LOG2E, b.w * LOG2E);
      qf[h][c] = u.v;
    }
  }

  // staging: thread covers row sr (0..63), cols sc..sc+31 (32 halves) of K & V^T
  const int sr = tid >> 1;
  const int sc = (tid & 1) << 5;

  s16x8 kpre[4];   // fp16 bits held as shorts
  s16x8 vpre[4];

  auto prefetch = [&](int kt) {
    if constexpr (PRE) {
      const _Float16* kg = Kg16 + (size_t)(kt * BC + sr) * HDIM + sc;
      kpre[0] = *(const s16x8*)(kg);
      kpre[1] = *(const s16x8*)(kg + 8);
      kpre[2] = *(const s16x8*)(kg + 16);
      kpre[3] = *(const s16x8*)(kg + 24);
      const short* vg = Vg16 + (size_t)sr * SEQ + kt * BC + sc;
      vpre[0] = *(const s16x8*)(vg);
      vpre[1] = *(const s16x8*)(vg + 8);
      vpre[2] = *(const s16x8*)(vg + 16);
      vpre[3] = *(const s16x8*)(vg + 24);
    }
  };
  auto commit = [&](int kt) {
    if constexpr (PRE) {
      *(s16x8*)&Ks[sr * KP + sc] = kpre[0];
      *(s16x8*)&Ks[sr * KP + sc + 8] = kpre[1];
      *(s16x8*)&Ks[sr * KP + sc + 16] = kpre[2];
      *(s16x8*)&Ks[sr * KP + sc + 24] = kpre[3];
      *(s16x8*)&Vs[sr * KP + sc] = vpre[0];
      *(s16x8*)&Vs[sr * KP + sc + 8] = vpre[1];
      *(s16x8*)&Vs[sr * KP + sc + 16] = vpre[2];
      *(s16x8*)&Vs[sr * KP + sc + 24] = vpre[3];
    } else {
      const float* kg = Kf + (size_t)(kt * BC + sr) * HDIM + sc;
      #pragma unroll
      for (int q4 = 0; q4 < 4; ++q4) {
        float4 a = *(const float4*)(kg + q4 * 8);
        float4 b = *(const float4*)(kg + q4 * 8 + 4);
        union { f16x8 v; f16x2 h2[4]; } ka;
        ka.h2[0] = pkrtz(a.x, a.y);
        ka.h2[1] = pkrtz(a.z, a.w);
        ka.h2[2] = pkrtz(b.x, b.y);
        ka.h2[3] = pkrtz(b.z, b.w);
        *(f16x8*)&Ks[sr * KP + sc + q4 * 8] = ka.v;
      }
      const float* vg = Vf + (size_t)(kt * BC + sr) * HDIM + sc;
      #pragma unroll
      for (int q4 = 0; q4 < 8; ++q4) {
        float4 v = *(const float4*)(vg + q4 * 4);
        Vs[(sc + q4 * 4 + 0) * KP + sr] = (short)f2bf(v.x);
        Vs[(sc + q4 * 4 + 1) * KP + sr] = (short)f2bf(v.y);
        Vs[(sc + q4 * 4 + 2) * KP + sr] = (short)f2bf(v.z);
        Vs[(sc + q4 * 4 + 3) * KP + sr] = (short)f2bf(v.w);
      }
    }
  };

  f32x4 acc[NH][4];
  #pragma unroll
  for (int h = 0; h < NH; ++h)
    #pragma unroll
    for (int nt = 0; nt < 4; ++nt)
      #pragma unroll
      for (int i = 0; i < 4; ++i) acc[h][nt][i] = 0.f;
  float l_[NH] = {0.f, 0.f, 0.f, 0.f};
  float negM[NH] = {0.f, 0.f, 0.f, 0.f};  // 0 for tile 0, then -M

  prefetch(0);
  commit(0);

  for (int it = 0; it < SEQ / BC; ++it) {
    __syncthreads();            // staged tile visible
    if (it < SEQ / BC - 1) prefetch(it + 1);

    // ---- S^T - M = K (Q*log2e)^T + C(-M) : D[kv=16jt+4g+ri][q=l16] ----
    f32x4 s[NH][4];
    #pragma unroll
    for (int jt = 0; jt < 4; ++jt) {
      const int ka = (jt * 16 + l16) * KP + g * 8;
      f16x8 k0 = *(const f16x8*)&Ks[ka];
      f16x8 k1 = *(const f16x8*)&Ks[ka + 32];
      #pragma unroll
      for (int h = 0; h < NH; ++h) {
        f32x4 z;
        z[0] = z[1] = z[2] = z[3] = negM[h];   // -M folded into C
        z = __builtin_amdgcn_mfma_f32_16x16x32_f16(k0, qf[h][0], z, 0, 0, 0);
        z = __builtin_amdgcn_mfma_f32_16x16x32_f16(k1, qf[h][1], z, 0, 0, 0);
        s[h][jt] = z;
      }
    }

    // ---- tile 0 only: derive per-row static M ----
    if (it == 0) {
      #pragma unroll
      for (int h = 0; h < NH; ++h) {
        float mx = s[h][0][0];
        #pragma unroll
        for (int jt = 0; jt < 4; ++jt)
          #pragma unroll
          for (int ri = 0; ri < 4; ++ri) mx = fmaxf(mx, s[h][jt][ri]);
        mx = fmaxf(mx, __shfl_xor(mx, 16));
        mx = fmaxf(mx, __shfl_xor(mx, 32));
        negM[h] = -(mx + MPAD);
        #pragma unroll
        for (int jt = 0; jt < 4; ++jt)
          #pragma unroll
          for (int ri = 0; ri < 4; ++ri) s[h][jt][ri] += negM[h];
      }
    }

    // ---- P = exp2(S - M) in bf16 (never clips), fp32 psum ----
    #pragma unroll
    for (int h = 0; h < NH; ++h) {
      float psum = l_[h];
      const int e0 = l16 * PP + 4 * g;
      #pragma unroll
      for (int jt = 0; jt < 4; ++jt) {
        float p0 = fast_exp2(s[h][jt][0]);
        float p1 = fast_exp2(s[h][jt][1]);
        float p2 = fast_exp2(s[h][jt][2]);
        float p3 = fast_exp2(s[h][jt][3]);
        psum += (p0 + p1) + (p2 + p3);
        uint2 w;
        w.x = bfpack2(p0, p1);
        w.y = bfpack2(p2, p3);
        *(uint2*)&Ps[wave][h][e0 + jt * 16] = w;   // contiguous kv: b64 store
      }
      l_[h] = psum;
    }

    // ---- O += P V  (A = P bf16, B = V^T bf16) ----
    s16x8 pa[NH][2];
    #pragma unroll
    for (int h = 0; h < NH; ++h) {
      pa[h][0] = *(const s16x8*)&Ps[wave][h][l16 * PP + g * 8];
      pa[h][1] = *(const s16x8*)&Ps[wave][h][l16 * PP + g * 8 + 32];
    }
    #pragma unroll
    for (int nt = 0; nt < 4; ++nt) {
      const int va = (nt * 16 + l16) * KP + g * 8;
      s16x8 v0 = *(const s16x8*)&Vs[va];
      s16x8 v1 = *(const s16x8*)&Vs[va + 32];
      #pragma unroll
      for (int h = 0; h < NH; ++h) {
        acc[h][nt] = __builtin_amdgcn_mfma_f32_16x16x32_bf16(pa[h][0], v0, acc[h][nt], 0, 0, 0);
        acc[h][nt] = __builtin_amdgcn_mfma_f32_16x16x32_bf16(pa[h][1], v1, acc[h][nt], 0, 0, 0);
      }
    }

    __syncthreads();            // all Ks/Vs reads done
    if (it < SEQ / BC - 1) commit(it + 1);
  }

  // ---- epilogue: normalize, store fp32 ----
  #pragma unroll
  for (int h = 0; h < NH; ++h) {
    float lf = l_[h];
    lf += __shfl_xor(lf, 16);
    lf += __shfl_xor(lf, 32);
    float linv = 1.0f / lf;
    #pragma unroll
    for (int ri = 0; ri < 4; ++ri) {
      float lB = __shfl(linv, 4 * g + ri);
      const int row = qbase + h * 16 + 4 * g + ri;
      #pragma unroll
      for (int nt = 0; nt < 4; ++nt)
        O[(size_t)row * HDIM + nt * 16 + l16] = acc[h][nt][ri] * lB;
    }
  }
}

extern "C" void kernel_launch(void* const* d_in, const int* in_sizes, int n_in,
                              void* d_out, int out_size, void* d_ws, size_t ws_size,
                              hipStream_t stream) {
  const float* QKV = (const float*)d_in[0];
  float* Out = (float*)d_out;
  const size_t tensElems = (size_t)NHEADS * SEQ * HDIM;   // 4,194,304
  const size_t k16Bytes = tensElems * sizeof(_Float16);   // 8.39 MB
  const size_t vtBytes = tensElems * sizeof(short);       // 8.39 MB

  dim3 grid(NHEADS * (SEQ / BR));  // 512

  if (ws_size >= k16Bytes + vtBytes) {
    _Float16* K16 = (_Float16*)d_ws;
    short* Vt16 = (short*)((char*)d_ws + k16Bytes);
    hipLaunchKernelGGL(prep, dim3(3072), dim3(256), 0, stream, QKV, K16, Vt16);
    hipLaunchKernelGGL((flash_attn<true>), grid, dim3(128), 0, stream, QKV, K16,
                       Vt16, Out);
  } else {
    hipLaunchKernelGGL((flash_attn<false>), grid, dim3(128), 0, stream, QKV,
                       (const _Float16*)nullptr, (const short*)nullptr, Out);
  }
}